// Round 1
// baseline (20802.193 us; speedup 1.0000x reference)
//
#include <hip/hip_runtime.h>
#include <cstdint>
#include <cstddef>

#define TSTEPS 256
#define NB     256
#define NH     1024
#define NIN    105
#define KPAD   128
#define NOUT   33

using half8 = __attribute__((ext_vector_type(8))) _Float16;
using f32x4 = __attribute__((ext_vector_type(4))) float;

// ---------------------------------------------------------------------------
// K0: pack weights to fp16, fragment-major for mfma_f32_16x16x32_f16 B-operand.
//   B-frag: lane holds W[o = ntile*16 + (lane&15)][k = kk*32 + (lane>>4)*8 + j]
// Layouts in ws:
//   Wrecf: [64 ntile][32 kk][64 lane][8]   (1,048,576 halves, 2 MB)
//   Wcf:   [64 ntile][ 4 kk][64 lane][8]   (  131,072 halves) K padded 105->128
//   Wof:   [ 3 ntile][32 kk][64 lane][8]   (   49,152 halves) N padded 33->48
// ---------------------------------------------------------------------------
__global__ __launch_bounds__(256) void k_convert(
    const float* __restrict__ W_sens, const float* __restrict__ W_rule,
    const float* __restrict__ W_rec,  const float* __restrict__ W_out,
    _Float16* __restrict__ Wrecf, _Float16* __restrict__ Wcf,
    _Float16* __restrict__ Wof)
{
    int tid  = blockIdx.x * 256 + threadIdx.x;
    int lane = tid & 63;
    int orow = lane & 15;
    int col0 = (lane >> 4) * 8;
    if (tid < 64 * 32 * 64) {                       // W_rec
        int kk = (tid >> 6) & 31, n = tid >> 11;
        int o = n * 16 + orow, k0 = kk * 32 + col0;
        const float* s = W_rec + (size_t)o * NH + k0;
        _Float16* d = Wrecf + (size_t)tid * 8;
        #pragma unroll
        for (int j = 0; j < 8; ++j) d[j] = (_Float16)s[j];
    } else if (tid < 64 * 32 * 64 + 64 * 4 * 64) {  // [W_sens | W_rule | 0pad]
        int t2 = tid - 64 * 32 * 64;
        int kk = (t2 >> 6) & 3, n = t2 >> 8;
        int o = n * 16 + orow, k0 = kk * 32 + col0;
        _Float16* d = Wcf + (size_t)t2 * 8;
        #pragma unroll
        for (int j = 0; j < 8; ++j) {
            int k = k0 + j;
            float v = 0.f;
            if (k < 85)       v = W_sens[o * 85 + k];
            else if (k < NIN) v = W_rule[o * 20 + (k - 85)];
            d[j] = (_Float16)v;
        }
    } else {                                        // W_out, rows >=33 zero
        int t3 = tid - (64 * 32 * 64 + 64 * 4 * 64);
        int kk = (t3 >> 6) & 31, n = t3 >> 11;
        int o = n * 16 + orow, k0 = kk * 32 + col0;
        _Float16* d = Wof + (size_t)t3 * 8;
        #pragma unroll
        for (int j = 0; j < 8; ++j)
            d[j] = (o < NOUT) ? (_Float16)W_out[(size_t)o * NH + k0 + j]
                              : (_Float16)0.f;
    }
}

// ---------------------------------------------------------------------------
// K1: pre[R][h] = x[R,:105] @ Wc^T + b_sens + b_rec + noise   (in-place into
// the noise buffer; fp32). Grid (1024 M-blocks of 64 rows, 4 N-chunks of 256).
// ---------------------------------------------------------------------------
#define XS_STRIDE 136   // 64 rows * 136 halves; 272 B stride = 68 words ≡ 4 mod 32 banks
__global__ __launch_bounds__(256) void k_ingemm(
    const float* __restrict__ x, float* __restrict__ pre,
    const float* __restrict__ b_sens, const float* __restrict__ b_rec,
    const _Float16* __restrict__ Wcf)
{
    __shared__ _Float16 xs[64 * XS_STRIDE];
    int tid = threadIdx.x;
    int bm  = blockIdx.x;       // 0..1023
    int nc  = blockIdx.y;       // 0..3
    const float* xsrc = x + (size_t)bm * 64 * NIN;  // 64 rows contiguous
    for (int idx = tid; idx < 64 * NIN; idx += 256) {
        int r = idx / NIN, c = idx - r * NIN;
        xs[r * XS_STRIDE + c] = (_Float16)xsrc[idx];
    }
    for (int idx = tid; idx < 64 * (XS_STRIDE - NIN); idx += 256) {
        int r = idx / (XS_STRIDE - NIN);
        int c = NIN + (idx - r * (XS_STRIDE - NIN));
        xs[r * XS_STRIDE + c] = (_Float16)0.f;      // zero K-pad
    }
    __syncthreads();

    int wave = tid >> 6, lane = tid & 63;
    int mrow = lane & 15, q = lane >> 4;
    f32x4 acc[16];
    #pragma unroll
    for (int nt = 0; nt < 16; ++nt) acc[nt] = (f32x4){0.f, 0.f, 0.f, 0.f};
    const half8* Wc8 = (const half8*)Wcf;

    #pragma unroll
    for (int kk = 0; kk < 4; ++kk) {
        half8 a = *(const half8*)&xs[(wave * 16 + mrow) * XS_STRIDE + kk * 32 + q * 8];
        #pragma unroll
        for (int nt = 0; nt < 16; ++nt) {
            int ng = nc * 16 + nt;
            half8 b = Wc8[(ng * 4 + kk) * 64 + lane];
            acc[nt] = __builtin_amdgcn_mfma_f32_16x16x32_f16(a, b, acc[nt], 0, 0, 0);
        }
    }
    #pragma unroll
    for (int nt = 0; nt < 16; ++nt) {
        int o = nc * 256 + nt * 16 + mrow;
        float bias = b_sens[o] + b_rec[o];
        #pragma unroll
        for (int r = 0; r < 4; ++r) {
            size_t R = (size_t)bm * 64 + wave * 16 + q * 4 + r;
            size_t ad = R * NH + o;
            pre[ad] = acc[nt][r] + bias + pre[ad];   // pre[ad] read = orig noise
        }
    }
}

// ---------------------------------------------------------------------------
// K2: the scan. 16 blocks x 512 thr (8 waves). Block g owns batch rows
// [g*16, g*16+16). Wave w owns output cols [w*128, (w+1)*128) (8 N-tiles).
// Master h fp32 in registers; fp16 copy in LDS for MFMA A-frags.
// Per step: 2048 MFMAs (h @ W_rec^T) + fused y = h @ W_out^T (waves 0-2).
// ---------------------------------------------------------------------------
#define HS 1032  // 1024 + 8 halves pad: 2064 B stride = 516 words ≡ 4 mod 32 banks
__global__ __launch_bounds__(512, 2) void k_rnn(
    const float* __restrict__ pre, const _Float16* __restrict__ Wrecf,
    const _Float16* __restrict__ Wof, const float* __restrict__ b_out,
    float* __restrict__ y)
{
    __shared__ _Float16 hbf[16 * HS];
    int tid = threadIdx.x;
    int g = blockIdx.x;
    int wave = tid >> 6, lane = tid & 63;
    int mrow = lane & 15, q = lane >> 4;

    for (int i = tid; i < 16 * HS; i += 512) hbf[i] = (_Float16)0.f;

    float hreg[8][4];
    #pragma unroll
    for (int j = 0; j < 8; ++j)
        #pragma unroll
        for (int r = 0; r < 4; ++r) hreg[j][r] = 0.f;

    const half8* Wr8 = (const half8*)Wrecf;
    const half8* Wo8 = (const half8*)Wof;

    // pre for t=0
    float prevA[8][4];
    #pragma unroll
    for (int j = 0; j < 8; ++j) {
        int o = wave * 128 + j * 16 + mrow;
        #pragma unroll
        for (int r = 0; r < 4; ++r)
            prevA[j][r] = pre[(size_t)(g * 16 + q * 4 + r) * NH + o];
    }
    __syncthreads();

    for (int t = 0; t < TSTEPS; ++t) {
        // Issue next step's pre loads NOW (HBM latency hidden behind K-loop).
        int tn = (t + 1 < TSTEPS) ? (t + 1) : t;
        float prevB[8][4];
        #pragma unroll
        for (int j = 0; j < 8; ++j) {
            int o = wave * 128 + j * 16 + mrow;
            #pragma unroll
            for (int r = 0; r < 4; ++r) {
                size_t R = (size_t)tn * NB + g * 16 + q * 4 + r;
                prevB[j][r] = pre[R * NH + o];
            }
        }

        f32x4 acc[8];
        #pragma unroll
        for (int j = 0; j < 8; ++j) acc[j] = (f32x4){0.f, 0.f, 0.f, 0.f};

        // K-loop, depth-2 software pipeline on B-frags (L2 latency ~200 cyc).
        half8 bb[2][8];
        #pragma unroll
        for (int j = 0; j < 8; ++j) {
            bb[0][j] = Wr8[((wave * 8 + j) * 32 + 0) * 64 + lane];
            bb[1][j] = Wr8[((wave * 8 + j) * 32 + 1) * 64 + lane];
        }
        #pragma unroll
        for (int kk = 0; kk < 32; ++kk) {
            half8 a = *(const half8*)&hbf[mrow * HS + kk * 32 + q * 8];
            #pragma unroll
            for (int j = 0; j < 8; ++j)
                acc[j] = __builtin_amdgcn_mfma_f32_16x16x32_f16(a, bb[kk & 1][j], acc[j], 0, 0, 0);
            if (kk + 2 < 32) {
                #pragma unroll
                for (int j = 0; j < 8; ++j)
                    bb[kk & 1][j] = Wr8[((wave * 8 + j) * 32 + (kk + 2)) * 64 + lane];
            }
        }
        __syncthreads();   // all A-frag reads of h_{t-1} complete

        // h update: v = recur + pre; h = 0.2*softplus(v) + 0.8*h  (fp32 master)
        #pragma unroll
        for (int j = 0; j < 8; ++j) {
            int o = wave * 128 + j * 16 + mrow;
            #pragma unroll
            for (int r = 0; r < 4; ++r) {
                float v  = acc[j][r] + prevA[j][r];
                float sp = fmaxf(v, 0.f) + __logf(1.f + __expf(-fabsf(v)));
                float hn = 0.2f * sp + 0.8f * hreg[j][r];
                hreg[j][r] = hn;
                hbf[(q * 4 + r) * HS + o] = (_Float16)hn;
            }
        }
        #pragma unroll
        for (int j = 0; j < 8; ++j)
            #pragma unroll
            for (int r = 0; r < 4; ++r) prevA[j][r] = prevB[j][r];
        __syncthreads();   // h_t visible to all waves

        // fused output: y[t] = h_t @ W_out^T + b_out  (waves 0..2: 48 cols pad)
        if (wave < 3) {
            f32x4 ya = (f32x4){0.f, 0.f, 0.f, 0.f};
            #pragma unroll
            for (int kk = 0; kk < 32; ++kk) {
                half8 a = *(const half8*)&hbf[mrow * HS + kk * 32 + q * 8];
                half8 b = Wo8[(wave * 32 + kk) * 64 + lane];
                ya = __builtin_amdgcn_mfma_f32_16x16x32_f16(a, b, ya, 0, 0, 0);
            }
            int o = wave * 16 + mrow;
            if (o < NOUT) {
                float bo = b_out[o];
                #pragma unroll
                for (int r = 0; r < 4; ++r) {
                    size_t R = (size_t)t * NB + g * 16 + q * 4 + r;
                    y[R * NOUT + o] = ya[r] + bo;
                }
            }
        }
    }
}

// ---------------------------------------------------------------------------
extern "C" void kernel_launch(void* const* d_in, const int* in_sizes, int n_in,
                              void* d_out, int out_size, void* d_ws, size_t ws_size,
                              hipStream_t stream) {
    const float* x      = (const float*)d_in[0];
    float*       noise  = (float*)d_in[1];   // overwritten in-place with `pre`
    const float* W_sens = (const float*)d_in[2];
    const float* b_sens = (const float*)d_in[3];
    const float* W_rule = (const float*)d_in[4];
    const float* W_rec  = (const float*)d_in[5];
    const float* b_rec  = (const float*)d_in[6];
    const float* W_out  = (const float*)d_in[7];
    const float* b_out  = (const float*)d_in[8];
    float*       y      = (float*)d_out;

    _Float16* wsp   = (_Float16*)d_ws;
    _Float16* Wrecf = wsp;                    // 1,048,576 halves
    _Float16* Wcf   = Wrecf + 64 * 32 * 64 * 8; //   131,072 halves
    _Float16* Wof   = Wcf   + 64 * 4 * 64 * 8;  //    49,152 halves

    k_convert<<<dim3(600), dim3(256), 0, stream>>>(W_sens, W_rule, W_rec, W_out,
                                                   Wrecf, Wcf, Wof);
    k_ingemm<<<dim3(1024, 4), dim3(256), 0, stream>>>(x, noise, b_sens, b_rec, Wcf);
    k_rnn<<<dim3(16), dim3(512), 0, stream>>>(noise, Wrecf, Wof, b_out, y);
}

// Round 2
// 4198.434 us; speedup vs baseline: 4.9547x; 4.9547x over previous
//
#include <hip/hip_runtime.h>
#include <cstdint>
#include <cstddef>

#define TSTEPS 256
#define NB     256
#define NH     1024
#define NIN    105
#define NOUT   33

using half8 = __attribute__((ext_vector_type(8))) _Float16;
using f32x4 = __attribute__((ext_vector_type(4))) float;

// ws layout (in halves):
//   Wrecf [0, 1048576)            : [64 nt][32 kk][64 lane][8]
//   Wcf   [1048576, 1179648)      : [64 nt][ 4 kk][64 lane][8]
//   Wof   [1179648, 1228800)      : [ 3 nt][32 kk][64 lane][8]
//   hG    [1228800, 1753088)      : [2 buf][16 kc][256 R][64 c]  fp16 h exchange
//   arr   (int*) at half-ofs 1753088 : [64 slots][16 ints] arrival flags

// ---------------------------------------------------------------------------
__global__ __launch_bounds__(256) void k_convert(
    const float* __restrict__ W_sens, const float* __restrict__ W_rule,
    const float* __restrict__ W_rec,  const float* __restrict__ W_out,
    _Float16* __restrict__ Wrecf, _Float16* __restrict__ Wcf,
    _Float16* __restrict__ Wof)
{
    int tid  = blockIdx.x * 256 + threadIdx.x;
    int lane = tid & 63;
    int orow = lane & 15;
    int col0 = (lane >> 4) * 8;
    if (tid < 64 * 32 * 64) {                       // W_rec
        int kk = (tid >> 6) & 31, n = tid >> 11;
        int o = n * 16 + orow, k0 = kk * 32 + col0;
        const float* s = W_rec + (size_t)o * NH + k0;
        _Float16* d = Wrecf + (size_t)tid * 8;
        #pragma unroll
        for (int j = 0; j < 8; ++j) d[j] = (_Float16)s[j];
    } else if (tid < 64 * 32 * 64 + 64 * 4 * 64) {  // [W_sens | W_rule | 0pad]
        int t2 = tid - 64 * 32 * 64;
        int kk = (t2 >> 6) & 3, n = t2 >> 8;
        int o = n * 16 + orow, k0 = kk * 32 + col0;
        _Float16* d = Wcf + (size_t)t2 * 8;
        #pragma unroll
        for (int j = 0; j < 8; ++j) {
            int k = k0 + j;
            float v = 0.f;
            if (k < 85)       v = W_sens[o * 85 + k];
            else if (k < NIN) v = W_rule[o * 20 + (k - 85)];
            d[j] = (_Float16)v;
        }
    } else {                                        // W_out, rows >=33 zero
        int t3 = tid - (64 * 32 * 64 + 64 * 4 * 64);
        int kk = (t3 >> 6) & 31, n = t3 >> 11;
        int o = n * 16 + orow, k0 = kk * 32 + col0;
        _Float16* d = Wof + (size_t)t3 * 8;
        #pragma unroll
        for (int j = 0; j < 8; ++j)
            d[j] = (o < NOUT) ? (_Float16)W_out[(size_t)o * NH + k0 + j]
                              : (_Float16)0.f;
    }
}

// zero hG (both buffers) + arrival flags
__global__ __launch_bounds__(256) void k_init(uint32_t* __restrict__ hGw,
                                              uint32_t* __restrict__ arrw)
{
    int tid = blockIdx.x * 256 + threadIdx.x;
    if (tid < 262144) hGw[tid] = 0u;        // 524288 halves
    if (tid < 1024)   arrw[tid] = 0u;       // 64 slots * 16 ints
}

// ---------------------------------------------------------------------------
// K1: pre = x@Wc^T + b_sens + b_rec + noise  (in-place into noise, fp32)
// ---------------------------------------------------------------------------
#define XS_STRIDE 136
__global__ __launch_bounds__(256) void k_ingemm(
    const float* __restrict__ x, float* __restrict__ pre,
    const float* __restrict__ b_sens, const float* __restrict__ b_rec,
    const _Float16* __restrict__ Wcf)
{
    __shared__ _Float16 xs[64 * XS_STRIDE];
    int tid = threadIdx.x;
    int bm  = blockIdx.x;
    int nc  = blockIdx.y;
    const float* xsrc = x + (size_t)bm * 64 * NIN;
    for (int idx = tid; idx < 64 * NIN; idx += 256) {
        int r = idx / NIN, c = idx - r * NIN;
        xs[r * XS_STRIDE + c] = (_Float16)xsrc[idx];
    }
    for (int idx = tid; idx < 64 * (XS_STRIDE - NIN); idx += 256) {
        int r = idx / (XS_STRIDE - NIN);
        int c = NIN + (idx - r * (XS_STRIDE - NIN));
        xs[r * XS_STRIDE + c] = (_Float16)0.f;
    }
    __syncthreads();

    int wave = tid >> 6, lane = tid & 63;
    int mrow = lane & 15, q = lane >> 4;
    f32x4 acc[16];
    #pragma unroll
    for (int nt = 0; nt < 16; ++nt) acc[nt] = (f32x4){0.f, 0.f, 0.f, 0.f};
    const half8* Wc8 = (const half8*)Wcf;

    #pragma unroll
    for (int kk = 0; kk < 4; ++kk) {
        half8 a = *(const half8*)&xs[(wave * 16 + mrow) * XS_STRIDE + kk * 32 + q * 8];
        #pragma unroll
        for (int nt = 0; nt < 16; ++nt) {
            int ng = nc * 16 + nt;
            half8 b = Wc8[(ng * 4 + kk) * 64 + lane];
            acc[nt] = __builtin_amdgcn_mfma_f32_16x16x32_f16(a, b, acc[nt], 0, 0, 0);
        }
    }
    #pragma unroll
    for (int nt = 0; nt < 16; ++nt) {
        int o = nc * 256 + nt * 16 + mrow;
        float bias = b_sens[o] + b_rec[o];
        #pragma unroll
        for (int r = 0; r < 4; ++r) {
            size_t R = (size_t)bm * 64 + wave * 16 + q * 4 + r;
            size_t ad = R * NH + o;
            pre[ad] = acc[nt][r] + bias + pre[ad];
        }
    }
}

// ---------------------------------------------------------------------------
// K2: the scan. 64 blocks = 4 groups(64 batch rows) x 16 slices(64 cols).
// W_rec slice LDS-resident (128 KB). Wave = (m in 0..3, khalf in 0..1):
// mtile m, K-half kh, all 4 ntiles; K-partials reduced via LDS.
// h exchanged through global fp16 dbuf hG[(t+1)&1]; per-group flag barrier.
// h (fp32) also written over pre[t] for the post-scan output GEMM.
// ---------------------------------------------------------------------------
__global__ __launch_bounds__(512, 1) void k_rnn(
    float* __restrict__ pre, const _Float16* __restrict__ Wrecf,
    _Float16* __restrict__ hG, int* __restrict__ arr)
{
    __shared__ _Float16 Wl[4 * 32 * 64 * 8];   // 128 KB, [nt][kk][lane][8]
    __shared__ float red[4][64][20];           // 20 KB K-partial exchange

    int tid  = threadIdx.x;
    int blk  = blockIdx.x;
    int g    = blk >> 4, s = blk & 15;
    int wave = tid >> 6, lane = tid & 63;
    int m    = wave & 3, kh = wave >> 2;
    int mrow = lane & 15, q = lane >> 4;

    // One-time: fill W slice (ntiles 4s..4s+4 -> contiguous 128 KB)
    {
        const float4* src = (const float4*)(Wrecf + (size_t)(4 * s) * 32 * 64 * 8);
        float4* dst = (float4*)Wl;
        for (int i = tid; i < 8192; i += 512) dst[i] = src[i];
    }
    __syncthreads();

    float hm[16];
    #pragma unroll
    for (int i = 0; i < 16; ++i) hm[i] = 0.f;

    // per-lane invariants
    int   rowg    = g * 64 + m * 16;                    // group row base of mtile
    size_t rowbase = (size_t)(rowg + mrow) * 64 + q * 8; // A addr within a kc plane

    for (int t = 0; t < TSTEPS; ++t) {
        const _Float16* hR = hG + (size_t)(t & 1) * (16 * 256 * 64);
        _Float16*       hW = hG + (size_t)((t + 1) & 1) * (16 * 256 * 64);

        // prefetch pre[t] for this block's tile (consumers: kh==0 waves)
        float pv[16];
        if (kh == 0) {
            #pragma unroll
            for (int nt = 0; nt < 4; ++nt)
                #pragma unroll
                for (int r = 0; r < 4; ++r)
                    pv[nt * 4 + r] = pre[((size_t)t * NB + rowg + q * 4 + r) * NH
                                         + s * 64 + nt * 16 + mrow];
        }

        // ---- K-loop: 16 kkl; A from hR (global/L2), B from LDS-resident Wl
        f32x4 acc[4];
        #pragma unroll
        for (int nt = 0; nt < 4; ++nt) acc[nt] = (f32x4){0.f, 0.f, 0.f, 0.f};

        half8 Abuf[8];
        #pragma unroll
        for (int i = 0; i < 8; ++i)
            Abuf[i] = *(const half8*)(hR + (size_t)(kh * 8 + (i >> 1)) * 16384
                                         + rowbase + (i & 1) * 32);
        #pragma unroll
        for (int kkl = 0; kkl < 16; ++kkl) {
            half8 a = Abuf[kkl & 7];
            if (kkl + 8 < 16)
                Abuf[kkl & 7] = *(const half8*)(hR + (size_t)(kh * 8 + ((kkl + 8) >> 1)) * 16384
                                                   + rowbase + ((kkl + 8) & 1) * 32);
            #pragma unroll
            for (int nt = 0; nt < 4; ++nt) {
                half8 b = *(const half8*)&Wl[((nt * 32 + kh * 16 + kkl) * 64 + lane) * 8];
                acc[nt] = __builtin_amdgcn_mfma_f32_16x16x32_f16(a, b, acc[nt], 0, 0, 0);
            }
        }

        // ---- reduce K-halves via LDS
        if (kh == 1) {
            #pragma unroll
            for (int nt = 0; nt < 4; ++nt)
                *(f32x4*)&red[m][lane][nt * 4] = acc[nt];
        }
        __syncthreads();

        if (kh == 0) {
            #pragma unroll
            for (int nt = 0; nt < 4; ++nt) {
                f32x4 p = *(const f32x4*)&red[m][lane][nt * 4];
                #pragma unroll
                for (int r = 0; r < 4; ++r) {
                    float v  = acc[nt][r] + p[r] + pv[nt * 4 + r];
                    float sp = fmaxf(v, 0.f) + __logf(1.f + __expf(-fabsf(v)));
                    float hn = 0.2f * sp + 0.8f * hm[nt * 4 + r];
                    hm[nt * 4 + r] = hn;
                    int R = rowg + q * 4 + r;
                    hW[((size_t)s * NB + R) * 64 + nt * 16 + mrow] = (_Float16)hn;
                    pre[((size_t)t * NB + R) * NH + s * 64 + nt * 16 + mrow] = hn;
                }
            }
            __threadfence();   // drain + make h_t writes device-visible
        }
        __syncthreads();

        // ---- inter-block barrier (group g: 16 slices)
        if (tid == 0)
            __hip_atomic_store(&arr[(g * 16 + s) * 16], t + 1,
                               __ATOMIC_RELEASE, __HIP_MEMORY_SCOPE_AGENT);
        if (wave == 0) {
            int idx = (g * 16 + (lane & 15)) * 16;
            for (int it = 0; it < (1 << 22); ++it) {
                int v = __hip_atomic_load(&arr[idx], __ATOMIC_ACQUIRE,
                                          __HIP_MEMORY_SCOPE_AGENT);
                if (__all(v >= t + 1)) break;
                __builtin_amdgcn_s_sleep(2);
            }
        }
        __syncthreads();
    }
}

// ---------------------------------------------------------------------------
// K3: y[t] = h[t] @ W_out^T + b_out, reading fp32 h states from pre buffer.
// ---------------------------------------------------------------------------
__global__ __launch_bounds__(256) void k_out(
    const float* __restrict__ h, const _Float16* __restrict__ Wof,
    const float* __restrict__ b_out, float* __restrict__ y)
{
    int blk  = blockIdx.x;                     // 1024 blocks of 64 rows
    int wave = threadIdx.x >> 6, lane = threadIdx.x & 63;
    int mrow = lane & 15, q = lane >> 4;
    size_t row = (size_t)blk * 64 + wave * 16 + mrow;   // A row for this lane
    const half8* Wo8 = (const half8*)Wof;

    f32x4 acc[3];
    #pragma unroll
    for (int nt = 0; nt < 3; ++nt) acc[nt] = (f32x4){0.f, 0.f, 0.f, 0.f};

    #pragma unroll 4
    for (int kk = 0; kk < 32; ++kk) {
        const float4* hp = (const float4*)(h + row * NH + kk * 32 + q * 8);
        float4 f0 = hp[0], f1 = hp[1];
        half8 a = { (_Float16)f0.x, (_Float16)f0.y, (_Float16)f0.z, (_Float16)f0.w,
                    (_Float16)f1.x, (_Float16)f1.y, (_Float16)f1.z, (_Float16)f1.w };
        #pragma unroll
        for (int nt = 0; nt < 3; ++nt) {
            half8 b = Wo8[(nt * 32 + kk) * 64 + lane];
            acc[nt] = __builtin_amdgcn_mfma_f32_16x16x32_f16(a, b, acc[nt], 0, 0, 0);
        }
    }
    #pragma unroll
    for (int nt = 0; nt < 3; ++nt) {
        int o = nt * 16 + mrow;
        if (o < NOUT) {
            float bo = b_out[o];
            #pragma unroll
            for (int r = 0; r < 4; ++r) {
                size_t R = (size_t)blk * 64 + wave * 16 + q * 4 + r;
                y[R * NOUT + o] = acc[nt][r] + bo;
            }
        }
    }
}

// ---------------------------------------------------------------------------
extern "C" void kernel_launch(void* const* d_in, const int* in_sizes, int n_in,
                              void* d_out, int out_size, void* d_ws, size_t ws_size,
                              hipStream_t stream) {
    const float* x      = (const float*)d_in[0];
    float*       noise  = (float*)d_in[1];   // becomes pre, then h states
    const float* W_sens = (const float*)d_in[2];
    const float* b_sens = (const float*)d_in[3];
    const float* W_rule = (const float*)d_in[4];
    const float* W_rec  = (const float*)d_in[5];
    const float* b_rec  = (const float*)d_in[6];
    const float* W_out  = (const float*)d_in[7];
    const float* b_out  = (const float*)d_in[8];
    float*       y      = (float*)d_out;

    _Float16* wsp   = (_Float16*)d_ws;
    _Float16* Wrecf = wsp;                          // 1,048,576 halves
    _Float16* Wcf   = Wrecf + 1048576;              //   131,072 halves
    _Float16* Wof   = Wcf   + 131072;               //    49,152 halves
    _Float16* hG    = Wof   + 49152;                //   524,288 halves
    int*      arr   = (int*)(hG + 524288);          //     1,024 ints

    k_convert<<<dim3(600), dim3(256), 0, stream>>>(W_sens, W_rule, W_rec, W_out,
                                                   Wrecf, Wcf, Wof);
    k_init<<<dim3(1024), dim3(256), 0, stream>>>((uint32_t*)hG, (uint32_t*)arr);
    k_ingemm<<<dim3(1024, 4), dim3(256), 0, stream>>>(x, noise, b_sens, b_rec, Wcf);
    k_rnn<<<dim3(64), dim3(512), 0, stream>>>(noise, Wrecf, hG, arr);
    k_out<<<dim3(1024), dim3(256), 0, stream>>>(noise, Wof, b_out, y);
}

// Round 3
// 1791.206 us; speedup vs baseline: 11.6135x; 2.3439x over previous
//
#include <hip/hip_runtime.h>
#include <cstdint>
#include <cstddef>

#define TSTEPS 256
#define NB     256
#define NH     1024
#define NIN    105
#define NOUT   33
#define NGRP   8    // batch groups of 32 rows; g = blk&7 -> XCD g under round-robin
#define NSL    16   // column slices of 64

using half8 = __attribute__((ext_vector_type(8))) _Float16;
using f32x4 = __attribute__((ext_vector_type(4))) float;

// ws layout (halves):
//   Wrecf [0,1048576)        [64 nt][32 kk][64 lane][8]
//   Wcf   +131072            [64 nt][ 4 kk][64 lane][8]
//   Wof   +49152             [ 3 nt][32 kk][64 lane][8]
//   hG    +524288            [2 buf][8 g][32 row][1024 col] fp16
//   arr   (int*) 128 flags; xcdArr (int*) 128

// ---------------------------------------------------------------------------
__global__ __launch_bounds__(256) void k_convert(
    const float* __restrict__ W_sens, const float* __restrict__ W_rule,
    const float* __restrict__ W_rec,  const float* __restrict__ W_out,
    _Float16* __restrict__ Wrecf, _Float16* __restrict__ Wcf,
    _Float16* __restrict__ Wof)
{
    int tid  = blockIdx.x * 256 + threadIdx.x;
    int lane = tid & 63;
    int orow = lane & 15;
    int col0 = (lane >> 4) * 8;
    if (tid < 64 * 32 * 64) {
        int kk = (tid >> 6) & 31, n = tid >> 11;
        int o = n * 16 + orow, k0 = kk * 32 + col0;
        const float* s = W_rec + (size_t)o * NH + k0;
        _Float16* d = Wrecf + (size_t)tid * 8;
        #pragma unroll
        for (int j = 0; j < 8; ++j) d[j] = (_Float16)s[j];
    } else if (tid < 64 * 32 * 64 + 64 * 4 * 64) {
        int t2 = tid - 64 * 32 * 64;
        int kk = (t2 >> 6) & 3, n = t2 >> 8;
        int o = n * 16 + orow, k0 = kk * 32 + col0;
        _Float16* d = Wcf + (size_t)t2 * 8;
        #pragma unroll
        for (int j = 0; j < 8; ++j) {
            int k = k0 + j;
            float v = 0.f;
            if (k < 85)       v = W_sens[o * 85 + k];
            else if (k < NIN) v = W_rule[o * 20 + (k - 85)];
            d[j] = (_Float16)v;
        }
    } else {
        int t3 = tid - (64 * 32 * 64 + 64 * 4 * 64);
        int kk = (t3 >> 6) & 31, n = t3 >> 11;
        int o = n * 16 + orow, k0 = kk * 32 + col0;
        _Float16* d = Wof + (size_t)t3 * 8;
        #pragma unroll
        for (int j = 0; j < 8; ++j)
            d[j] = (o < NOUT) ? (_Float16)W_out[(size_t)o * NH + k0 + j]
                              : (_Float16)0.f;
    }
}

__global__ __launch_bounds__(256) void k_init(uint32_t* __restrict__ hGw,
                                              uint32_t* __restrict__ flags)
{
    int tid = blockIdx.x * 256 + threadIdx.x;
    if (tid < 262144) hGw[tid] = 0u;   // hG both buffers (524288 halves)
    if (tid < 256)    flags[tid] = 0u; // arr[128] + xcdArr[128]
}

// ---------------------------------------------------------------------------
#define XS_STRIDE 136
__global__ __launch_bounds__(256) void k_ingemm(
    const float* __restrict__ x, float* __restrict__ pre,
    const float* __restrict__ b_sens, const float* __restrict__ b_rec,
    const _Float16* __restrict__ Wcf)
{
    __shared__ _Float16 xs[64 * XS_STRIDE];
    int tid = threadIdx.x;
    int bm  = blockIdx.x;
    int nc  = blockIdx.y;
    const float* xsrc = x + (size_t)bm * 64 * NIN;
    for (int idx = tid; idx < 64 * NIN; idx += 256) {
        int r = idx / NIN, c = idx - r * NIN;
        xs[r * XS_STRIDE + c] = (_Float16)xsrc[idx];
    }
    for (int idx = tid; idx < 64 * (XS_STRIDE - NIN); idx += 256) {
        int r = idx / (XS_STRIDE - NIN);
        int c = NIN + (idx - r * (XS_STRIDE - NIN));
        xs[r * XS_STRIDE + c] = (_Float16)0.f;
    }
    __syncthreads();

    int wave = tid >> 6, lane = tid & 63;
    int mrow = lane & 15, q = lane >> 4;
    f32x4 acc[16];
    #pragma unroll
    for (int nt = 0; nt < 16; ++nt) acc[nt] = (f32x4){0.f, 0.f, 0.f, 0.f};
    const half8* Wc8 = (const half8*)Wcf;

    #pragma unroll
    for (int kk = 0; kk < 4; ++kk) {
        half8 a = *(const half8*)&xs[(wave * 16 + mrow) * XS_STRIDE + kk * 32 + q * 8];
        #pragma unroll
        for (int nt = 0; nt < 16; ++nt) {
            int ng = nc * 16 + nt;
            half8 b = Wc8[(ng * 4 + kk) * 64 + lane];
            acc[nt] = __builtin_amdgcn_mfma_f32_16x16x32_f16(a, b, acc[nt], 0, 0, 0);
        }
    }
    #pragma unroll
    for (int nt = 0; nt < 16; ++nt) {
        int o = nc * 256 + nt * 16 + mrow;
        float bias = b_sens[o] + b_rec[o];
        #pragma unroll
        for (int r = 0; r < 4; ++r) {
            size_t R = (size_t)bm * 64 + wave * 16 + q * 4 + r;
            size_t ad = R * NH + o;
            pre[ad] = acc[nt][r] + bias + pre[ad];
        }
    }
}

// ---------------------------------------------------------------------------
// K2: 128 blocks = 8 groups(32 rows, g=blk&7 -> XCD-affine) x 16 slices(64 cols).
// Waves: m = w&1 (mtile), kq = w>>1 (K-quarter of 256). W slice LDS-resident.
// Fast path (group XCD-uniform): plain stores -> shared L2; buffer_inv sc0 (L1
// only) per step. Safe path: full agent acquire/release fences. Flags: relaxed
// agent atomics (poll), one ordering op per step.
// ---------------------------------------------------------------------------
__global__ __launch_bounds__(512, 1) void k_rnn(
    float* __restrict__ pre, const _Float16* __restrict__ Wrecf,
    _Float16* __restrict__ hG, int* __restrict__ arr, int* __restrict__ xcdArr)
{
    __shared__ _Float16 Wl[4 * 32 * 64 * 8];   // 128 KB [nt][kk][lane][8]
    __shared__ float red[8][64][4];            // 8 KB  [m*4+nt][lane][r]
    __shared__ int sFast;

    const int tid  = threadIdx.x;
    const int blk  = blockIdx.x;
    const int g    = blk & 7, s = blk >> 3;
    const int wave = tid >> 6, lane = tid & 63;
    const int m    = wave & 1, kq = wave >> 1;
    const int mrow = lane & 15, q = lane >> 4;

    // W slice: global ntiles [4s, 4s+4) -> contiguous 128 KB
    {
        const float4* src = (const float4*)(Wrecf + (size_t)(4 * s) * (32 * 64 * 8));
        float4* dst = (float4*)Wl;
        for (int i = tid; i < 8192; i += 512) dst[i] = src[i];
    }

    // ---- XCD uniformity check (runtime-select fast/safe path) ----
    int xcd;
    asm volatile("s_getreg_b32 %0, hwreg(20, 0, 4)" : "=s"(xcd)); // HW_REG_XCC_ID
    if (tid == 0)
        __hip_atomic_store(&xcdArr[blk], xcd + 1, __ATOMIC_RELEASE,
                           __HIP_MEMORY_SCOPE_AGENT);
    if (wave == 0) {
        int idx = g + (lane & 15) * 8;   // my group's 16 block ids: g + 8*s
        int v = 0;
        for (int it = 0; it < (1 << 22); ++it) {
            v = __hip_atomic_load(&xcdArr[idx], __ATOMIC_ACQUIRE,
                                  __HIP_MEMORY_SCOPE_AGENT);
            if (__all(v >= 1)) break;
            __builtin_amdgcn_s_sleep(8);
        }
        if (lane == 0) sFast = __all(v == xcd + 1) ? 1 : 0;
    }
    __syncthreads();
    const bool fast = (sFast != 0);

    float hm[4][4];   // kq0: fp32 master h
    float pA[4][4];   // kq0: pre tile for current t
    #pragma unroll
    for (int nt = 0; nt < 4; ++nt)
        #pragma unroll
        for (int r = 0; r < 4; ++r) hm[nt][r] = 0.f;
    if (kq == 0) {
        #pragma unroll
        for (int nt = 0; nt < 4; ++nt)
            #pragma unroll
            for (int r = 0; r < 4; ++r)
                pA[nt][r] = pre[(size_t)(g * 32 + m * 16 + q * 4 + r) * NH
                                + s * 64 + nt * 16 + mrow];
    }

    const size_t rowA = (size_t)(g * 32 + m * 16 + mrow);

    for (int t = 0; t < TSTEPS; ++t) {
        // ---- 1. wait for all 16 slices of my group at step t ----
        {
            int idx = g * 16 + (lane & 15);
            for (int it = 0; it < (1 << 22); ++it) {
                int v = __hip_atomic_load(&arr[idx], __ATOMIC_RELAXED,
                                          __HIP_MEMORY_SCOPE_AGENT);
                if (__all(v >= t)) break;
                __builtin_amdgcn_s_sleep(1);
            }
        }
        if (fast) {
            asm volatile("buffer_inv sc0" ::: "memory");  // L1 inv; L2 is fresh
        } else {
            __builtin_amdgcn_fence(__ATOMIC_ACQUIRE, "agent");
        }

        // ---- 2. K-loop: A from hG (L2), B from LDS-resident W slice ----
        const _Float16* hR = hG + (size_t)(t & 1) * (NGRP * 32 * 1024)
                                + rowA * 1024 + kq * 256 + q * 8;
        f32x4 acc[4];
        #pragma unroll
        for (int nt = 0; nt < 4; ++nt) acc[nt] = (f32x4){0.f, 0.f, 0.f, 0.f};
        #pragma unroll
        for (int kkl = 0; kkl < 8; ++kkl) {
            half8 a = *(const half8*)(hR + kkl * 32);
            #pragma unroll
            for (int nt = 0; nt < 4; ++nt) {
                half8 b = *(const half8*)&Wl[((nt * 32 + kq * 8 + kkl) * 64 + lane) * 8];
                acc[nt] = __builtin_amdgcn_mfma_f32_16x16x32_f16(a, b, acc[nt], 0, 0, 0);
            }
        }

        // ---- 3. reduce K-quarters into red (kq3 -> kq2 -> kq1 -> kq0) ----
        if (kq == 3) {
            #pragma unroll
            for (int nt = 0; nt < 4; ++nt)
                *(f32x4*)&red[m * 4 + nt][lane][0] = acc[nt];
        }
        __syncthreads();
        if (kq == 2) {
            #pragma unroll
            for (int nt = 0; nt < 4; ++nt) {
                f32x4 r = *(const f32x4*)&red[m * 4 + nt][lane][0];
                *(f32x4*)&red[m * 4 + nt][lane][0] = r + acc[nt];
            }
        }
        __syncthreads();
        if (kq == 1) {
            #pragma unroll
            for (int nt = 0; nt < 4; ++nt) {
                f32x4 r = *(const f32x4*)&red[m * 4 + nt][lane][0];
                *(f32x4*)&red[m * 4 + nt][lane][0] = r + acc[nt];
            }
        }
        __syncthreads();

        // ---- 4. update + publish (kq0 waves own the 32x64 tile) ----
        if (kq == 0) {
            _Float16* hW = hG + (size_t)((t + 1) & 1) * (NGRP * 32 * 1024);
            #pragma unroll
            for (int nt = 0; nt < 4; ++nt) {
                f32x4 rr = *(const f32x4*)&red[m * 4 + nt][lane][0];
                #pragma unroll
                for (int r = 0; r < 4; ++r) {
                    float v  = acc[nt][r] + rr[r] + pA[nt][r];
                    float sp = fmaxf(v, 0.f) + __logf(1.f + __expf(-fabsf(v)));
                    float hn = 0.2f * sp + 0.8f * hm[nt][r];
                    hm[nt][r] = hn;
                    int rl = m * 16 + q * 4 + r;          // 0..31 within group
                    int cl = s * 64 + nt * 16 + mrow;     // global col
                    hW[(size_t)(g * 32 + rl) * 1024 + cl] = (_Float16)hn;
                    pre[((size_t)t * NB + g * 32 + rl) * NH + cl] = hn; // h history
                }
            }
            // refill pA for t+1 (overlaps the sync/flag phase)
            if (t + 1 < TSTEPS) {
                #pragma unroll
                for (int nt = 0; nt < 4; ++nt)
                    #pragma unroll
                    for (int r = 0; r < 4; ++r)
                        pA[nt][r] = pre[((size_t)(t + 1) * NB + g * 32 + m * 16
                                         + q * 4 + r) * NH + s * 64 + nt * 16 + mrow];
            }
        }
        __syncthreads();   // full waitcnt drain + barrier: stores are in L2

        if (!fast && tid == 0)
            __builtin_amdgcn_fence(__ATOMIC_RELEASE, "agent"); // wbl2: push to IC
        if (tid == 0)
            __hip_atomic_store(&arr[g * 16 + s], t + 1, __ATOMIC_RELAXED,
                               __HIP_MEMORY_SCOPE_AGENT);
    }
}

// ---------------------------------------------------------------------------
__global__ __launch_bounds__(256) void k_out(
    const float* __restrict__ h, const _Float16* __restrict__ Wof,
    const float* __restrict__ b_out, float* __restrict__ y)
{
    int blk  = blockIdx.x;
    int wave = threadIdx.x >> 6, lane = threadIdx.x & 63;
    int mrow = lane & 15, q = lane >> 4;
    size_t row = (size_t)blk * 64 + wave * 16 + mrow;
    const half8* Wo8 = (const half8*)Wof;

    f32x4 acc[3];
    #pragma unroll
    for (int nt = 0; nt < 3; ++nt) acc[nt] = (f32x4){0.f, 0.f, 0.f, 0.f};

    #pragma unroll 4
    for (int kk = 0; kk < 32; ++kk) {
        const float4* hp = (const float4*)(h + row * NH + kk * 32 + q * 8);
        float4 f0 = hp[0], f1 = hp[1];
        half8 a = { (_Float16)f0.x, (_Float16)f0.y, (_Float16)f0.z, (_Float16)f0.w,
                    (_Float16)f1.x, (_Float16)f1.y, (_Float16)f1.z, (_Float16)f1.w };
        #pragma unroll
        for (int nt = 0; nt < 3; ++nt) {
            half8 b = Wo8[(nt * 32 + kk) * 64 + lane];
            acc[nt] = __builtin_amdgcn_mfma_f32_16x16x32_f16(a, b, acc[nt], 0, 0, 0);
        }
    }
    #pragma unroll
    for (int nt = 0; nt < 3; ++nt) {
        int o = nt * 16 + mrow;
        if (o < NOUT) {
            float bo = b_out[o];
            #pragma unroll
            for (int r = 0; r < 4; ++r) {
                size_t R = (size_t)blk * 64 + wave * 16 + q * 4 + r;
                y[R * NOUT + o] = acc[nt][r] + bo;
            }
        }
    }
}

// ---------------------------------------------------------------------------
extern "C" void kernel_launch(void* const* d_in, const int* in_sizes, int n_in,
                              void* d_out, int out_size, void* d_ws, size_t ws_size,
                              hipStream_t stream) {
    const float* x      = (const float*)d_in[0];
    float*       noise  = (float*)d_in[1];   // becomes pre, then h history
    const float* W_sens = (const float*)d_in[2];
    const float* b_sens = (const float*)d_in[3];
    const float* W_rule = (const float*)d_in[4];
    const float* W_rec  = (const float*)d_in[5];
    const float* b_rec  = (const float*)d_in[6];
    const float* W_out  = (const float*)d_in[7];
    const float* b_out  = (const float*)d_in[8];
    float*       y      = (float*)d_out;

    _Float16* wsp   = (_Float16*)d_ws;
    _Float16* Wrecf = wsp;
    _Float16* Wcf   = Wrecf + 1048576;
    _Float16* Wof   = Wcf   + 131072;
    _Float16* hG    = Wof   + 49152;               // 524288 halves (2 buffers)
    int*      arr   = (int*)(hG + 524288);         // 128 flags
    int*      xcdArr= arr + 128;                   // 128 xcd ids

    k_convert<<<dim3(600), dim3(256), 0, stream>>>(W_sens, W_rule, W_rec, W_out,
                                                   Wrecf, Wcf, Wof);
    k_init<<<dim3(1024), dim3(256), 0, stream>>>((uint32_t*)hG, (uint32_t*)arr);
    k_ingemm<<<dim3(1024, 4), dim3(256), 0, stream>>>(x, noise, b_sens, b_rec, Wcf);
    k_rnn<<<dim3(128), dim3(512), 0, stream>>>(noise, Wrecf, hG, arr, xcdArr);
    k_out<<<dim3(1024), dim3(256), 0, stream>>>(noise, Wof, b_out, y);
}